// Round 1
// baseline (446.654 us; speedup 1.0000x reference)
//
#include <hip/hip_runtime.h>

// Problem constants (fixed-shape problem)
constexpr int BS   = 16;
constexpr int F    = 4086;
constexpr int C    = 512;
constexpr int SPK  = 2;
constexpr int L    = 16;
constexpr int STEP = 8;                  // L/2
constexpr int T    = (F - 1) * STEP + L; // 32696
constexpr int ROWS = BS * F;             // 65376

constexpr int WAVES_PER_BLOCK = 4;
constexpr int BLOCK = 64 * WAVES_PER_BLOCK;
constexpr int WPAD = 20;                 // padded W row stride in floats (16 -> 20, keeps 16B align, kills bank conflicts)

__global__ __launch_bounds__(BLOCK, 1) void decoder_fused_kernel(
    const float* __restrict__ inp,   // [BS][F][C]
    const float* __restrict__ mask,  // [BS][F][C][SPK]
    const float* __restrict__ W,     // [C][L]
    float* __restrict__ out)         // [BS][SPK][T]
{
    __shared__ float w_lds[C * WPAD]; // 40 KB

    const int tid = threadIdx.x;

    // Stage W into LDS with padded rows (2 rows per thread)
    for (int r = tid; r < C; r += BLOCK) {
        const float4* src = reinterpret_cast<const float4*>(W + r * L);
        float4* dst = reinterpret_cast<float4*>(w_lds + r * WPAD);
        dst[0] = src[0];
        dst[1] = src[1];
        dst[2] = src[2];
        dst[3] = src[3];
    }
    __syncthreads();

    const int wave = tid >> 6;
    const int lane = tid & 63;
    const int row  = blockIdx.x * WAVES_PER_BLOCK + wave; // grid sized exactly
    const int b    = row / F;
    const int f    = row % F;

    const float*  inp_row  = inp + (size_t)row * C;
    const float2* mask_row = reinterpret_cast<const float2*>(mask) + (size_t)row * C;

    // Hoist all global loads (independent -> deep vmcnt pipeline)
    float  xi[8];
    float2 xm[8];
#pragma unroll
    for (int i = 0; i < 8; ++i) {
        const int c = lane + 64 * i;
        xi[i] = inp_row[c];
        xm[i] = mask_row[c];
    }

    float acc0[L];
    float acc1[L];
#pragma unroll
    for (int l = 0; l < L; ++l) { acc0[l] = 0.f; acc1[l] = 0.f; }

#pragma unroll
    for (int i = 0; i < 8; ++i) {
        const int c  = lane + 64 * i;
        const float x  = xi[i];
        const float p0 = x * xm[i].x;
        const float p1 = x * xm[i].y;
        const float4* wr = reinterpret_cast<const float4*>(&w_lds[c * WPAD]);
#pragma unroll
        for (int q = 0; q < 4; ++q) {
            const float4 wv = wr[q];
            acc0[4*q+0] = fmaf(p0, wv.x, acc0[4*q+0]);
            acc0[4*q+1] = fmaf(p0, wv.y, acc0[4*q+1]);
            acc0[4*q+2] = fmaf(p0, wv.z, acc0[4*q+2]);
            acc0[4*q+3] = fmaf(p0, wv.w, acc0[4*q+3]);
            acc1[4*q+0] = fmaf(p1, wv.x, acc1[4*q+0]);
            acc1[4*q+1] = fmaf(p1, wv.y, acc1[4*q+1]);
            acc1[4*q+2] = fmaf(p1, wv.z, acc1[4*q+2]);
            acc1[4*q+3] = fmaf(p1, wv.w, acc1[4*q+3]);
        }
    }

    // Fold reduction over 64 lanes: 32 values -> each lane ends with value v = lane&31
    float v[32];
#pragma unroll
    for (int l = 0; l < 16; ++l) { v[l] = acc0[l]; v[16 + l] = acc1[l]; }

#pragma unroll
    for (int m = 16; m >= 1; m >>= 1) {
        const bool hi = (lane & m) != 0;
#pragma unroll
        for (int i = 0; i < m; ++i) {
            const float send = hi ? v[i] : v[i + m];
            const float keep = hi ? v[i + m] : v[i];
            v[i] = keep + __shfl_xor(send, m, 64);
        }
    }
    float val = v[0] + __shfl_xor(v[0], 32, 64);

    // Overlap-add: frame f contributes to out[b][s][f*8 + l], exactly <=2 adds per cell
    if (lane < 32) {
        const int s = lane >> 4;
        const int l = lane & 15;
        atomicAdd(&out[(size_t)(b * SPK + s) * T + f * STEP + l], val);
    }
}

extern "C" void kernel_launch(void* const* d_in, const int* in_sizes, int n_in,
                              void* d_out, int out_size, void* d_ws, size_t ws_size,
                              hipStream_t stream) {
    const float* inp  = (const float*)d_in[0];
    const float* mask = (const float*)d_in[1];
    const float* W    = (const float*)d_in[2];
    float* out = (float*)d_out;

    // Zero output (it is accumulated into via atomics; harness poisons it)
    hipMemsetAsync(out, 0, (size_t)BS * SPK * T * sizeof(float), stream);

    const int grid = ROWS / WAVES_PER_BLOCK; // 16344 exactly
    decoder_fused_kernel<<<grid, BLOCK, 0, stream>>>(inp, mask, W, out);
}

// Round 2
// 86.419 us; speedup vs baseline: 5.1685x; 5.1685x over previous
//
#include <hip/hip_runtime.h>

// Fixed problem shape
constexpr int BS = 16, F = 4086, C = 512, SPK = 2, L = 16, STEP = 8;
constexpr int T    = (F - 1) * STEP + L;   // 32696
constexpr int ROWS = BS * F;               // 65376
constexpr int OUT_N = BS * SPK * T;        // 1046272
constexpr int WPAD = 20;                   // padded W row stride (proven 0 bank conflicts in r1)
constexpr int WAVES = 4;
constexpr int BLOCK = WAVES * 64;
constexpr int FR  = 4;                     // frames per wave (amortize W staging, prefetch depth)
constexpr int FPB = WAVES * FR;            // 16 frames per block
constexpr int GRID_A = ROWS / FPB;         // 4086 exactly

// ---- cross-lane helpers -----------------------------------------------------
// quad_perm DPP: xor1 = perm[1,0,3,2] -> ctrl 0xB1 ; xor2 = perm[2,3,0,1] -> ctrl 0x4E
template <int CTRL>
__device__ __forceinline__ float dppq(float x) {
    int i = __builtin_bit_cast(int, x);
    i = __builtin_amdgcn_update_dpp(i, i, CTRL, 0xf, 0xf, true);
    return __builtin_bit_cast(float, i);
}
// ds_swizzle BitMode: offset = (xor<<10) | 0x1F  (within 32-lane halves)
template <int OFF>
__device__ __forceinline__ float swz(float x) {
    int i = __builtin_bit_cast(int, x);
    i = __builtin_amdgcn_ds_swizzle(i, OFF);
    return __builtin_bit_cast(float, i);
}

// Ascending-mask butterfly fold of v[32] across 64 lanes.
// After the 5 levels lane L holds the sum (over its 32-lane half) of value
// index o(L) = 16*b0 + 8*b1 + 4*b2 + 2*b3 + b4 (bit-reversed 5-bit lane id);
// the final xor-32 shuffle adds the other half.
// (verified by lane-trace: lane 0 -> o=0, lane 1 -> o=16, lane 16 -> o=1)
__device__ __forceinline__ float fold32(float v[32], int lane) {
    const bool h1 = lane & 1, h2 = lane & 2, h4 = lane & 4, h8 = lane & 8, h16 = lane & 16;
#pragma unroll
    for (int i = 0; i < 16; ++i) {               // m=1 : DPP (VALU, no LDS)
        const float s = h1 ? v[i] : v[i + 16];
        const float k = h1 ? v[i + 16] : v[i];
        v[i] = k + dppq<0xB1>(s);
    }
#pragma unroll
    for (int i = 0; i < 8; ++i) {                // m=2 : DPP
        const float s = h2 ? v[i] : v[i + 8];
        const float k = h2 ? v[i + 8] : v[i];
        v[i] = k + dppq<0x4E>(s);
    }
#pragma unroll
    for (int i = 0; i < 4; ++i) {                // m=4 : ds_swizzle
        const float s = h4 ? v[i] : v[i + 4];
        const float k = h4 ? v[i + 4] : v[i];
        v[i] = k + swz<0x101F>(s);
    }
#pragma unroll
    for (int i = 0; i < 2; ++i) {                // m=8 : ds_swizzle
        const float s = h8 ? v[i] : v[i + 2];
        const float k = h8 ? v[i + 2] : v[i];
        v[i] = k + swz<0x201F>(s);
    }
    {                                            // m=16 : ds_swizzle
        const float s = h16 ? v[0] : v[1];
        const float k = h16 ? v[1] : v[0];
        v[0] = k + swz<0x401F>(s);
    }
    return v[0] + __shfl_xor(v[0], 32, 64);      // cross-half
}

// ---- kernel A: masked projection -> proj[row][32] (or atomic overlap-add) ---
template <bool USE_WS>
__global__ __launch_bounds__(BLOCK, 2) void decoder_proj_kernel(
    const float* __restrict__ inp,   // [BS][F][C]
    const float* __restrict__ mask,  // [BS][F][C][SPK]
    const float* __restrict__ W,     // [C][L]
    float* __restrict__ dst)         // USE_WS ? proj[ROWS][32] : out[BS][SPK][T]
{
    __shared__ float w_lds[C * WPAD]; // 40 KB

    const int tid = threadIdx.x;
    for (int r = tid; r < C; r += BLOCK) {
        const float4* src = reinterpret_cast<const float4*>(W + r * L);
        float4* d = reinterpret_cast<float4*>(w_lds + r * WPAD);
        d[0] = src[0]; d[1] = src[1]; d[2] = src[2]; d[3] = src[3];
    }
    __syncthreads();

    const int wave = tid >> 6, lane = tid & 63;
    const int row0 = blockIdx.x * FPB + wave * FR;

    // bit-reversed output index this lane owns after fold32
    const int o = ((lane & 1) << 4) | (((lane >> 1) & 1) << 3) | (((lane >> 2) & 1) << 2)
                | (((lane >> 3) & 1) << 1) | ((lane >> 4) & 1);

    float  xiA[8], xiB[8];
    float2 xmA[8], xmB[8];

    auto load = [&](int row, float* xi, float2* xm) {
        const float*  ir = inp + (size_t)row * C;
        const float2* mr = reinterpret_cast<const float2*>(mask) + (size_t)row * C;
#pragma unroll
        for (int i = 0; i < 8; ++i) {
            const int c = lane + 64 * i;   // coalesced: 256B / 512B per instr
            xi[i] = ir[c];
            xm[i] = mr[c];
        }
    };

    auto compute = [&](const float* xi, const float2* xm) -> float {
        float v[32];
#pragma unroll
        for (int j = 0; j < 32; ++j) v[j] = 0.f;
#pragma unroll
        for (int i = 0; i < 8; ++i) {
            const int c  = lane + 64 * i;
            const float p0 = xi[i] * xm[i].x;
            const float p1 = xi[i] * xm[i].y;
            const float4* wr = reinterpret_cast<const float4*>(&w_lds[c * WPAD]);
#pragma unroll
            for (int q = 0; q < 4; ++q) {
                const float4 wv = wr[q];
                v[4*q+0]    = fmaf(p0, wv.x, v[4*q+0]);
                v[4*q+1]    = fmaf(p0, wv.y, v[4*q+1]);
                v[4*q+2]    = fmaf(p0, wv.z, v[4*q+2]);
                v[4*q+3]    = fmaf(p0, wv.w, v[4*q+3]);
                v[16+4*q+0] = fmaf(p1, wv.x, v[16+4*q+0]);
                v[16+4*q+1] = fmaf(p1, wv.y, v[16+4*q+1]);
                v[16+4*q+2] = fmaf(p1, wv.z, v[16+4*q+2]);
                v[16+4*q+3] = fmaf(p1, wv.w, v[16+4*q+3]);
            }
        }
        return fold32(v, lane);
    };

    auto store = [&](int row, float val) {
        if (USE_WS) {
            if (lane < 32) dst[(size_t)row * 32 + o] = val;  // 128B contiguous per wave
        } else {
            if (lane < 32) {
                const int b = row / F, f = row % F;
                const int s = o >> 4, l = o & 15;
                atomicAdd(&dst[(size_t)(b * SPK + s) * T + f * STEP + l], val);
            }
        }
    };

    // explicit double-buffered pipeline over FR=4 frames (no runtime reg indexing)
    load(row0 + 0, xiA, xmA);
    load(row0 + 1, xiB, xmB);
    store(row0 + 0, compute(xiA, xmA));
    load(row0 + 2, xiA, xmA);
    store(row0 + 1, compute(xiB, xmB));
    load(row0 + 3, xiB, xmB);
    store(row0 + 2, compute(xiA, xmA));
    store(row0 + 3, compute(xiB, xmB));
}

// ---- kernel B: overlap-and-add gather (each output: <=2 reads, 1 write) -----
__global__ __launch_bounds__(256) void overlap_add_kernel(
    const float* __restrict__ proj,  // [ROWS][32]  (32 = s*16 + l)
    float* __restrict__ out)         // [BS][SPK][T]
{
    const int idx = blockIdx.x * blockDim.x + threadIdx.x;
    if (idx >= OUT_N) return;
    const int b = idx / (SPK * T);
    const int r = idx - b * (SPK * T);
    const int s = r / T;
    const int t = r - s * T;
    const int f0 = t >> 3, l0 = t & 7;
    float acc = 0.f;
    if (t < F * STEP) acc += proj[(size_t)(b * F + f0) * 32 + s * 16 + l0];       // frame f0, l=l0
    if (t >= STEP)    acc += proj[(size_t)(b * F + f0 - 1) * 32 + s * 16 + 8 + l0]; // frame f0-1, l=l0+8
    out[idx] = acc;
}

extern "C" void kernel_launch(void* const* d_in, const int* in_sizes, int n_in,
                              void* d_out, int out_size, void* d_ws, size_t ws_size,
                              hipStream_t stream) {
    const float* inp  = (const float*)d_in[0];
    const float* mask = (const float*)d_in[1];
    const float* W    = (const float*)d_in[2];
    float* out = (float*)d_out;

    const size_t need = (size_t)ROWS * 32 * sizeof(float); // 8.37 MB
    if (ws_size >= need) {
        float* proj = (float*)d_ws;
        decoder_proj_kernel<true><<<GRID_A, BLOCK, 0, stream>>>(inp, mask, W, proj);
        overlap_add_kernel<<<(OUT_N + 255) / 256, 256, 0, stream>>>(proj, out);
    } else {
        hipMemsetAsync(out, 0, (size_t)OUT_N * sizeof(float), stream);
        decoder_proj_kernel<false><<<GRID_A, BLOCK, 0, stream>>>(inp, mask, W, out);
    }
}